// Round 3
// baseline (128.871 us; speedup 1.0000x reference)
//
#include <hip/hip_runtime.h>
#include <math.h>

// Problem constants (fixed by setup_inputs)
#define B   16
#define L   512
#define H   768
#define HV4 192      // H/4 float4s per row
#define S1  32
#define S2  128
#define NS  8
#define M   4
#define CH  16       // L-chunk rows per partial block
#define NCHUNK 32    // L / CH

// ---------------------------------------------------------------------------
// K1 (fused pool): 2048 blocks, 192 threads.
//   bid < 1024 : half-row partial masked sums of expl_h1+expl_h2
//                (i = bid>>1, j in [64*(bid&1), 64*(bid&1)+64)) -> rc_part/rc_cnt.
//                1024 blocks = 4/CU, 12 waves/CU -> ~96KB in flight/CU.
//   bid < 1536 : sent partial masked sums over 16-row chunks
//   else       : sel span partial sums over 16-row chunks
// ---------------------------------------------------------------------------
__global__ __launch_bounds__(192)
void k_pool(const float* __restrict__ e1, const float* __restrict__ e2,
            const int* __restrict__ am,
            const float* __restrict__ s1, const float* __restrict__ s2,
            const int* __restrict__ iam,
            const float* __restrict__ hs, const int* __restrict__ st_,
            const int* __restrict__ en_,
            float* __restrict__ rc_part, float* __restrict__ rc_cnt,
            float* __restrict__ sp_part, float* __restrict__ sp_cnt,
            float* __restrict__ sel_part, float* __restrict__ sel_cnt) {
  const int bid = blockIdx.x;
  const int t = threadIdx.x;
  if (bid < 1024) {
    const int i = bid >> 1;
    const int jbase = (bid & 1) * 64;
    __shared__ float mk[64];
    __shared__ int   idxL[64];
    __shared__ float mvL[64];
    __shared__ int   cntS;
    if (t < 64) mk[t] = (float)am[i * S2 + jbase + t];
    __syncthreads();
    if (t == 0) {
      int c = 0; float s = 0.f;
      for (int j = 0; j < 64; ++j) {
        float m = mk[j]; s += m;
        if (m != 0.f) { idxL[c] = jbase + j; mvL[c] = m; ++c; }
      }
      cntS = c; rc_cnt[bid] = s;
    }
    __syncthreads();
    const int cnt = cntS;
    const float4* p1 = (const float4*)e1 + (size_t)i * (S2 * HV4);
    const float4* p2 = (const float4*)e2 + (size_t)i * (S2 * HV4);
    float ax = 0.f, ay = 0.f, az = 0.f, aw = 0.f;
    int kk = 0;
    for (; kk + 3 < cnt; kk += 4) {
      int j0 = idxL[kk], j1 = idxL[kk + 1], j2 = idxL[kk + 2], j3 = idxL[kk + 3];
      float m0 = mvL[kk], m1 = mvL[kk + 1], m2 = mvL[kk + 2], m3 = mvL[kk + 3];
      float4 a0 = p1[j0 * HV4 + t], b0 = p2[j0 * HV4 + t];
      float4 a1 = p1[j1 * HV4 + t], b1 = p2[j1 * HV4 + t];
      float4 a2 = p1[j2 * HV4 + t], b2 = p2[j2 * HV4 + t];
      float4 a3 = p1[j3 * HV4 + t], b3 = p2[j3 * HV4 + t];
      ax += m0 * (a0.x + b0.x) + m1 * (a1.x + b1.x) + m2 * (a2.x + b2.x) + m3 * (a3.x + b3.x);
      ay += m0 * (a0.y + b0.y) + m1 * (a1.y + b1.y) + m2 * (a2.y + b2.y) + m3 * (a3.y + b3.y);
      az += m0 * (a0.z + b0.z) + m1 * (a1.z + b1.z) + m2 * (a2.z + b2.z) + m3 * (a3.z + b3.z);
      aw += m0 * (a0.w + b0.w) + m1 * (a1.w + b1.w) + m2 * (a2.w + b2.w) + m3 * (a3.w + b3.w);
    }
    for (; kk < cnt; ++kk) {
      int j = idxL[kk]; float m = mvL[kk];
      float4 a = p1[j * HV4 + t], b = p2[j * HV4 + t];
      ax += m * (a.x + b.x); ay += m * (a.y + b.y);
      az += m * (a.z + b.z); aw += m * (a.w + b.w);
    }
    float4 o; o.x = ax; o.y = ay; o.z = az; o.w = aw;
    ((float4*)rc_part)[(size_t)bid * HV4 + t] = o;
  } else if (bid < 1536) {
    const int blk = bid - 1024;
    const int b = blk >> 5, c = blk & 31;
    __shared__ float mk2[CH];
    __shared__ int   idx2[CH];
    __shared__ float mv2[CH];
    __shared__ int   cnt2;
    if (t < CH) mk2[t] = (float)iam[b * L + c * CH + t];
    __syncthreads();
    if (t == 0) {
      int cc = 0; float s = 0.f;
      for (int l = 0; l < CH; ++l) {
        float m = mk2[l]; s += m;
        if (m != 0.f) { idx2[cc] = l; mv2[cc] = m; ++cc; }
      }
      cnt2 = cc; sp_cnt[blk] = s;
    }
    __syncthreads();
    const int cn = cnt2;
    const float4* p1 = (const float4*)s1 + ((size_t)b * L + c * CH) * HV4;
    const float4* p2 = (const float4*)s2 + ((size_t)b * L + c * CH) * HV4;
    float ax = 0.f, ay = 0.f, az = 0.f, aw = 0.f;
    int kk = 0;
    for (; kk + 1 < cn; kk += 2) {
      int l0 = idx2[kk], l1 = idx2[kk + 1];
      float m0 = mv2[kk], m1 = mv2[kk + 1];
      float4 a0 = p1[l0 * HV4 + t], b0 = p2[l0 * HV4 + t];
      float4 a1 = p1[l1 * HV4 + t], b1 = p2[l1 * HV4 + t];
      ax += m0 * (a0.x + b0.x) + m1 * (a1.x + b1.x);
      ay += m0 * (a0.y + b0.y) + m1 * (a1.y + b1.y);
      az += m0 * (a0.z + b0.z) + m1 * (a1.z + b1.z);
      aw += m0 * (a0.w + b0.w) + m1 * (a1.w + b1.w);
    }
    for (; kk < cn; ++kk) {
      int l = idx2[kk]; float m = mv2[kk];
      float4 a = p1[l * HV4 + t], b = p2[l * HV4 + t];
      ax += m * (a.x + b.x); ay += m * (a.y + b.y);
      az += m * (a.z + b.z); aw += m * (a.w + b.w);
    }
    float4 o; o.x = ax; o.y = ay; o.z = az; o.w = aw;
    ((float4*)sp_part)[(size_t)blk * HV4 + t] = o;
  } else {
    const int blk = bid - 1536;
    const int b = blk >> 5, c = blk & 31;
    const int st = st_[b], en = en_[b];
    int lo = st > c * CH ? st : c * CH;
    int hi = en < c * CH + CH ? en : c * CH + CH;
    const float4* p = (const float4*)hs + (size_t)b * L * HV4;
    float ax = 0.f, ay = 0.f, az = 0.f, aw = 0.f;
    int l = lo;
    for (; l + 1 < hi; l += 2) {
      float4 a0 = p[l * HV4 + t];
      float4 a1 = p[(l + 1) * HV4 + t];
      ax += a0.x + a1.x; ay += a0.y + a1.y; az += a0.z + a1.z; aw += a0.w + a1.w;
    }
    if (l < hi) {
      float4 a0 = p[l * HV4 + t];
      ax += a0.x; ay += a0.y; az += a0.z; aw += a0.w;
    }
    float4 o; o.x = ax; o.y = ay; o.z = az; o.w = aw;
    ((float4*)sel_part)[(size_t)blk * HV4 + t] = o;
    if (t == 0) sel_cnt[blk] = (float)(hi > lo ? hi - lo : 0);
  }
}

// ---------------------------------------------------------------------------
// K2: q[b, 64-h tile] = sp[b,:] @ W_attn. Grid 192 blocks (b x 12 h-tiles),
// 256 threads, d split 4-way per block. sp re-derived from sp_part (L2).
// ---------------------------------------------------------------------------
__global__ __launch_bounds__(256)
void k_q(const float* __restrict__ sp_part, const float* __restrict__ sp_cnt,
         const float* __restrict__ W_attn, float* __restrict__ q) {
  __shared__ float spL[H];
  __shared__ float red[256];
  const int qb = blockIdx.x, t = threadIdx.x;
  const int b = qb / 12, ht = qb % 12;
  float csp = 0.f;
  for (int c = 0; c < NCHUNK; ++c) csp += sp_cnt[b * NCHUNK + c];
  const float inv = 1.f / csp;
  #pragma unroll
  for (int k = 0; k < 3; ++k) {
    const int h = t + k * 256;
    float a = 0.f;
    for (int c = 0; c < NCHUNK; ++c)
      a += sp_part[((size_t)b * NCHUNK + c) * H + h];
    spL[h] = a * inv;
  }
  __syncthreads();
  const int hl = t & 63, dseg = t >> 6;
  const int h = ht * 64 + hl;
  const float* wp = W_attn + (size_t)(dseg * 192) * H + h;
  const float* sv = spL + dseg * 192;
  float acc = 0.f;
  #pragma unroll 4
  for (int i = 0; i < 192; ++i) acc += sv[i] * wp[(size_t)i * H];
  red[t] = acc;
  __syncthreads();
  if (t < 64)
    q[(size_t)b * H + ht * 64 + t] = red[t] + red[t + 64] + red[t + 128] + red[t + 192];
}

// ---------------------------------------------------------------------------
// K3 (fused sims+softmax+pooled+transform): grid 192 (b x 12 h-tiles), 256 thr.
// Each block redundantly computes the cheap per-b attention (32 sims from
// rc_part in L2), then its 64-h stripe of y = pooled @ W_t^T + b_t.
// ---------------------------------------------------------------------------
__global__ __launch_bounds__(256)
void k_attn_transform(const float* __restrict__ rc_part, const float* __restrict__ rc_cnt,
                      const float* __restrict__ q, const int* __restrict__ extra_index,
                      const float* __restrict__ W_t, const float* __restrict__ b_t,
                      float* __restrict__ yb) {
  const int bid = blockIdx.x, t = threadIdx.x;
  const int b = bid / 12, ht = bid % 12;
  const int lane = t & 63, w = t >> 6;
  __shared__ float qL[H];
  __shared__ float pL[NS * H];      // pooled, 24 KiB
  __shared__ float waveRed[S1 * 4];
  __shared__ float invL[S1];
  __shared__ float simL[S1];
  __shared__ float w2[S1];          // softmax weight * inv(count)
  #pragma unroll
  for (int k = 0; k < 3; ++k) qL[t + k * 256] = q[(size_t)b * H + t + k * 256];
  __syncthreads();
  // --- sims: acc[m] = sum_d qL[d] * (p0[d]+p1[d]) over this thread's 3 d's
  const float* rcb = rc_part + (size_t)(b * 64) * H;
  float acc[S1];
  #pragma unroll
  for (int m = 0; m < S1; ++m) {
    float a = 0.f;
    const float* r0 = rcb + (size_t)(2 * m) * H;
    const float* r1 = rcb + (size_t)(2 * m + 1) * H;
    #pragma unroll
    for (int k = 0; k < 3; ++k) {
      const int d = t + k * 256;
      a += qL[d] * (r0[d] + r1[d]);
    }
    acc[m] = a;
  }
  #pragma unroll
  for (int m = 0; m < S1; ++m) {
    float v = acc[m];
    v += __shfl_down(v, 32); v += __shfl_down(v, 16); v += __shfl_down(v, 8);
    v += __shfl_down(v, 4);  v += __shfl_down(v, 2);  v += __shfl_down(v, 1);
    if (lane == 0) waveRed[m * 4 + w] = v;
  }
  __syncthreads();
  if (t < S1) {
    const float tot = waveRed[t * 4] + waveRed[t * 4 + 1] + waveRed[t * 4 + 2] + waveRed[t * 4 + 3];
    const float inv = 1.f / (rc_cnt[b * 64 + 2 * t] + rc_cnt[b * 64 + 2 * t + 1]);
    invL[t] = inv;
    simL[t] = tot * inv * 0.036084391824351615f;  // 1/sqrt(768)
  }
  __syncthreads();
  if (t < NS) {
    const int vid = extra_index[b * NS + t];
    float x[M], mx = -1e30f;
    #pragma unroll
    for (int m = 0; m < M; ++m) {
      x[m] = (m < vid) ? simL[t * M + m] : -1e30f;
      mx = fmaxf(mx, x[m]);
    }
    float s = 0.f, e[M];
    #pragma unroll
    for (int m = 0; m < M; ++m) { e[m] = expf(x[m] - mx); s += e[m]; }
    #pragma unroll
    for (int m = 0; m < M; ++m) w2[t * M + m] = (e[m] / s) * invL[t * M + m];
  }
  __syncthreads();
  // --- pooled[n,d] = sum_m w2[n,m] * (p0+p1)[n*4+m][d]
  #pragma unroll
  for (int k = 0; k < 3; ++k) {
    const int d = t + k * 256;
    #pragma unroll
    for (int n = 0; n < NS; ++n) {
      float p = 0.f;
      #pragma unroll
      for (int m = 0; m < M; ++m) {
        const int i2 = (n * M + m) * 2;
        p += w2[n * M + m] * (rcb[(size_t)i2 * H + d] + rcb[(size_t)(i2 + 1) * H + d]);
      }
      pL[n * H + d] = p;
    }
  }
  __syncthreads();
  // --- transform: y[n, h] for h in this 64-tile
  const int n0 = t >> 6;            // wave-uniform n -> LDS broadcast
  const int h = ht * 64 + lane;
  const float4* wr = (const float4*)(W_t + (size_t)h * H);
  const float4* pr0 = (const float4*)(pL + n0 * H);
  const float4* pr1 = (const float4*)(pL + (n0 + 4) * H);
  float acc0 = 0.f, acc1 = 0.f;
  #pragma unroll 4
  for (int d = 0; d < HV4; ++d) {
    float4 ww = wr[d];
    float4 p0 = pr0[d], p1 = pr1[d];
    acc0 += ww.x * p0.x + ww.y * p0.y + ww.z * p0.z + ww.w * p0.w;
    acc1 += ww.x * p1.x + ww.y * p1.y + ww.z * p1.z + ww.w * p1.w;
  }
  const float bias = b_t[h];
  yb[((size_t)b * NS + n0) * H + h] = acc0 + bias;
  yb[((size_t)b * NS + n0 + 4) * H + h] = acc1 + bias;
}

// ---------------------------------------------------------------------------
// K4: sel combine + LayerNorm(gamma_s) fused with row-LN(gamma_t) + cosine
// score (cls_out never materialized). Grid: B blocks, 256 threads.
// ---------------------------------------------------------------------------
__global__ __launch_bounds__(256)
void k_lnscore(const float* __restrict__ sel_part, const float* __restrict__ sel_cnt,
               const float* __restrict__ gamma_s, const float* __restrict__ beta_s,
               const float* __restrict__ yb, const float* __restrict__ gamma_t,
               const float* __restrict__ beta_t, float* __restrict__ out) {
  const int b = blockIdx.x, t = threadIdx.x;
  __shared__ float red[256];
  __shared__ float mv[2];
  // sel combine + LN
  float csel = 0.f;
  for (int c = 0; c < NCHUNK; ++c) csel += sel_cnt[b * NCHUNK + c];
  float selv[3];
  #pragma unroll
  for (int k = 0; k < 3; ++k) {
    const int h = t + k * 256;
    float s = 0.f;
    for (int c = 0; c < NCHUNK; ++c)
      s += sel_part[((size_t)b * NCHUNK + c) * H + h];
    selv[k] = s / csel;
  }
  red[t] = selv[0] + selv[1] + selv[2];
  __syncthreads();
  for (int s = 128; s > 0; s >>= 1) { if (t < s) red[t] += red[t + s]; __syncthreads(); }
  if (t == 0) mv[0] = red[0] / (float)H;
  __syncthreads();
  float mu = mv[0];
  float lv = 0.f;
  #pragma unroll
  for (int k = 0; k < 3; ++k) { float d = selv[k] - mu; lv += d * d; }
  red[t] = lv;
  __syncthreads();
  for (int s = 128; s > 0; s >>= 1) { if (t < s) red[t] += red[t + s]; __syncthreads(); }
  if (t == 0) mv[1] = red[0] / (float)H;
  __syncthreads();
  float rstd = rsqrtf(mv[1] + 1e-12f);
  float sl[3];
  #pragma unroll
  for (int k = 0; k < 3; ++k) {
    const int h = t + k * 256;
    sl[k] = (selv[k] - mu) * rstd * gamma_s[h] + beta_s[h];
  }
  __syncthreads();
  // per-row LN of y + S/SS accumulation
  float g[3], be[3];
  #pragma unroll
  for (int k = 0; k < 3; ++k) { g[k] = gamma_t[t + k * 256]; be[k] = beta_t[t + k * 256]; }
  float S[3] = {0.f, 0.f, 0.f}, SS[3] = {0.f, 0.f, 0.f};
  for (int n = 0; n < NS; ++n) {
    float v[3];
    #pragma unroll
    for (int k = 0; k < 3; ++k) v[k] = yb[((size_t)b * NS + n) * H + t + k * 256];
    red[t] = v[0] + v[1] + v[2];
    __syncthreads();
    for (int s = 128; s > 0; s >>= 1) { if (t < s) red[t] += red[t + s]; __syncthreads(); }
    if (t == 0) mv[0] = red[0] / (float)H;
    __syncthreads();
    const float mun = mv[0];
    float lvn = 0.f;
    #pragma unroll
    for (int k = 0; k < 3; ++k) { float d = v[k] - mun; lvn += d * d; }
    red[t] = lvn;
    __syncthreads();
    for (int s = 128; s > 0; s >>= 1) { if (t < s) red[t] += red[t + s]; __syncthreads(); }
    if (t == 0) mv[1] = red[0] / (float)H;
    __syncthreads();
    const float rstdn = rsqrtf(mv[1] + 1e-12f);
    #pragma unroll
    for (int k = 0; k < 3; ++k) {
      const float c = (v[k] - mun) * rstdn * g[k] + be[k];
      S[k] += c; SS[k] += c * c;
    }
    __syncthreads();
  }
  #pragma unroll
  for (int k = 0; k < 3; ++k) {
    const int h = t + k * 256;
    const float n1 = 2.8284271247461903f * fabsf(sl[k]);  // sqrt(8)*|sel|
    const float n2 = sqrtf(SS[k]);
    out[(size_t)b * H + h] = sl[k] * S[k] / (fmaxf(n1, 1e-8f) * fmaxf(n2, 1e-8f));
  }
}

// ---------------------------------------------------------------------------
extern "C" void kernel_launch(void* const* d_in, const int* in_sizes, int n_in,
                              void* d_out, int out_size, void* d_ws, size_t ws_size,
                              hipStream_t stream) {
  const float* hidden_states = (const float*)d_in[0];
  const float* sent_h1       = (const float*)d_in[1];
  const float* sent_h2       = (const float*)d_in[2];
  const int*   attention_mask= (const int*)  d_in[3];
  const float* expl_h1       = (const float*)d_in[4];
  const float* expl_h2       = (const float*)d_in[5];
  const int*   extra_am      = (const int*)  d_in[6];
  const int*   extra_index   = (const int*)  d_in[7];
  const int*   extra_start   = (const int*)  d_in[8];
  const int*   extra_end     = (const int*)  d_in[9];
  const float* W_attn        = (const float*)d_in[10];
  const float* W_t           = (const float*)d_in[11];
  const float* b_t           = (const float*)d_in[12];
  const float* gamma_t       = (const float*)d_in[13];
  const float* beta_t        = (const float*)d_in[14];
  const float* gamma_s       = (const float*)d_in[15];
  const float* beta_s        = (const float*)d_in[16];
  float* out = (float*)d_out;

  float* ws = (float*)d_ws;
  float* rc_part  = ws;                        // 1024*768
  float* rc_cnt   = rc_part + 1024 * H;        // 1024
  float* sp_part  = rc_cnt + 1024;             // 512*768
  float* sp_cnt   = sp_part + 512 * H;         // 512
  float* sel_part = sp_cnt + 512;              // 512*768
  float* sel_cnt  = sel_part + 512 * H;        // 512
  float* q        = sel_cnt + 512;             // 16*768
  float* yb       = q + B * H;                 // 128*768

  k_pool<<<2048, 192, 0, stream>>>(expl_h1, expl_h2, extra_am,
                                   sent_h1, sent_h2, attention_mask,
                                   hidden_states, extra_start, extra_end,
                                   rc_part, rc_cnt, sp_part, sp_cnt,
                                   sel_part, sel_cnt);
  k_q<<<192, 256, 0, stream>>>(sp_part, sp_cnt, W_attn, q);
  k_attn_transform<<<192, 256, 0, stream>>>(rc_part, rc_cnt, q, extra_index,
                                            W_t, b_t, yb);
  k_lnscore<<<B, 256, 0, stream>>>(sel_part, sel_cnt, gamma_s, beta_s,
                                   yb, gamma_t, beta_t, out);
}

// Round 4
// 123.733 us; speedup vs baseline: 1.0415x; 1.0415x over previous
//
#include <hip/hip_runtime.h>
#include <math.h>

// Problem constants (fixed by setup_inputs)
#define B   16
#define L   512
#define H   768
#define HV4 192      // H/4 float4s per row
#define S1  32
#define S2  128
#define NS  8
#define M   4
#define CH  16       // L-chunk rows per partial block
#define NCHUNK 32    // L / CH

// ---------------------------------------------------------------------------
// K1 (fused): 1536 blocks, 192 threads.  [R2-validated]
//   bid <  512 : row_cls masked mean over expl_h1+expl_h2 (the ~200MB stream)
//   bid < 1024 : sent partial masked sums over 16-row chunks
//   else       : sel span partial sums over 16-row chunks
// ---------------------------------------------------------------------------
__global__ __launch_bounds__(192)
void k_pool(const float* __restrict__ e1, const float* __restrict__ e2,
            const int* __restrict__ am,
            const float* __restrict__ s1, const float* __restrict__ s2,
            const int* __restrict__ iam,
            const float* __restrict__ hs, const int* __restrict__ st_,
            const int* __restrict__ en_,
            float* __restrict__ row_cls,
            float* __restrict__ sp_part, float* __restrict__ sp_cnt,
            float* __restrict__ sel_part, float* __restrict__ sel_cnt) {
  const int bid = blockIdx.x;
  const int t = threadIdx.x;
  if (bid < 512) {
    const int i = bid;
    __shared__ float mk[S2];
    __shared__ int   idxL[S2];
    __shared__ float mvL[S2];
    __shared__ int   cntS;
    __shared__ float msumS;
    if (t < S2) mk[t] = (float)am[i * S2 + t];
    __syncthreads();
    if (t == 0) {
      int c = 0; float s = 0.f;
      for (int j = 0; j < S2; ++j) {
        float m = mk[j]; s += m;
        if (m != 0.f) { idxL[c] = j; mvL[c] = m; ++c; }
      }
      cntS = c; msumS = s;
    }
    __syncthreads();
    const int cnt = cntS;
    const float4* p1 = (const float4*)e1 + (size_t)i * (S2 * HV4);
    const float4* p2 = (const float4*)e2 + (size_t)i * (S2 * HV4);
    float ax = 0.f, ay = 0.f, az = 0.f, aw = 0.f;
    int kk = 0;
    for (; kk + 3 < cnt; kk += 4) {
      int j0 = idxL[kk], j1 = idxL[kk + 1], j2 = idxL[kk + 2], j3 = idxL[kk + 3];
      float m0 = mvL[kk], m1 = mvL[kk + 1], m2 = mvL[kk + 2], m3 = mvL[kk + 3];
      float4 a0 = p1[j0 * HV4 + t], b0 = p2[j0 * HV4 + t];
      float4 a1 = p1[j1 * HV4 + t], b1 = p2[j1 * HV4 + t];
      float4 a2 = p1[j2 * HV4 + t], b2 = p2[j2 * HV4 + t];
      float4 a3 = p1[j3 * HV4 + t], b3 = p2[j3 * HV4 + t];
      ax += m0 * (a0.x + b0.x) + m1 * (a1.x + b1.x) + m2 * (a2.x + b2.x) + m3 * (a3.x + b3.x);
      ay += m0 * (a0.y + b0.y) + m1 * (a1.y + b1.y) + m2 * (a2.y + b2.y) + m3 * (a3.y + b3.y);
      az += m0 * (a0.z + b0.z) + m1 * (a1.z + b1.z) + m2 * (a2.z + b2.z) + m3 * (a3.z + b3.z);
      aw += m0 * (a0.w + b0.w) + m1 * (a1.w + b1.w) + m2 * (a2.w + b2.w) + m3 * (a3.w + b3.w);
    }
    for (; kk < cnt; ++kk) {
      int j = idxL[kk]; float m = mvL[kk];
      float4 a = p1[j * HV4 + t], b = p2[j * HV4 + t];
      ax += m * (a.x + b.x); ay += m * (a.y + b.y);
      az += m * (a.z + b.z); aw += m * (a.w + b.w);
    }
    float inv = 1.f / msumS;
    float4 o; o.x = ax * inv; o.y = ay * inv; o.z = az * inv; o.w = aw * inv;
    ((float4*)row_cls)[(size_t)i * HV4 + t] = o;
  } else if (bid < 1024) {
    const int blk = bid - 512;
    const int b = blk >> 5, c = blk & 31;
    __shared__ float mk2[CH];
    __shared__ int   idx2[CH];
    __shared__ float mv2[CH];
    __shared__ int   cnt2;
    if (t < CH) mk2[t] = (float)iam[b * L + c * CH + t];
    __syncthreads();
    if (t == 0) {
      int cc = 0; float s = 0.f;
      for (int l = 0; l < CH; ++l) {
        float m = mk2[l]; s += m;
        if (m != 0.f) { idx2[cc] = l; mv2[cc] = m; ++cc; }
      }
      cnt2 = cc; sp_cnt[blk] = s;
    }
    __syncthreads();
    const int cn = cnt2;
    const float4* p1 = (const float4*)s1 + ((size_t)b * L + c * CH) * HV4;
    const float4* p2 = (const float4*)s2 + ((size_t)b * L + c * CH) * HV4;
    float ax = 0.f, ay = 0.f, az = 0.f, aw = 0.f;
    int kk = 0;
    for (; kk + 1 < cn; kk += 2) {
      int l0 = idx2[kk], l1 = idx2[kk + 1];
      float m0 = mv2[kk], m1 = mv2[kk + 1];
      float4 a0 = p1[l0 * HV4 + t], b0 = p2[l0 * HV4 + t];
      float4 a1 = p1[l1 * HV4 + t], b1 = p2[l1 * HV4 + t];
      ax += m0 * (a0.x + b0.x) + m1 * (a1.x + b1.x);
      ay += m0 * (a0.y + b0.y) + m1 * (a1.y + b1.y);
      az += m0 * (a0.z + b0.z) + m1 * (a1.z + b1.z);
      aw += m0 * (a0.w + b0.w) + m1 * (a1.w + b1.w);
    }
    for (; kk < cn; ++kk) {
      int l = idx2[kk]; float m = mv2[kk];
      float4 a = p1[l * HV4 + t], b = p2[l * HV4 + t];
      ax += m * (a.x + b.x); ay += m * (a.y + b.y);
      az += m * (a.z + b.z); aw += m * (a.w + b.w);
    }
    float4 o; o.x = ax; o.y = ay; o.z = az; o.w = aw;
    ((float4*)sp_part)[(size_t)blk * HV4 + t] = o;
  } else {
    const int blk = bid - 1024;
    const int b = blk >> 5, c = blk & 31;
    const int st = st_[b], en = en_[b];
    int lo = st > c * CH ? st : c * CH;
    int hi = en < c * CH + CH ? en : c * CH + CH;
    const float4* p = (const float4*)hs + (size_t)b * L * HV4;
    float ax = 0.f, ay = 0.f, az = 0.f, aw = 0.f;
    int l = lo;
    for (; l + 1 < hi; l += 2) {
      float4 a0 = p[l * HV4 + t];
      float4 a1 = p[(l + 1) * HV4 + t];
      ax += a0.x + a1.x; ay += a0.y + a1.y; az += a0.z + a1.z; aw += a0.w + a1.w;
    }
    if (l < hi) {
      float4 a0 = p[l * HV4 + t];
      ax += a0.x; ay += a0.y; az += a0.z; aw += a0.w;
    }
    float4 o; o.x = ax; o.y = ay; o.z = az; o.w = aw;
    ((float4*)sel_part)[(size_t)blk * HV4 + t] = o;
    if (t == 0) sel_cnt[blk] = (float)(hi > lo ? hi - lo : 0);
  }
}

// ---------------------------------------------------------------------------
// K2: q[b, 64-h tile] = sp[b,:] @ W_attn. Grid 192 blocks (b x 12 h-tiles),
// 256 threads, d split 4-way per block.  [R3-validated]
// ---------------------------------------------------------------------------
__global__ __launch_bounds__(256)
void k_q(const float* __restrict__ sp_part, const float* __restrict__ sp_cnt,
         const float* __restrict__ W_attn, float* __restrict__ q) {
  __shared__ float spL[H];
  __shared__ float red[256];
  const int qb = blockIdx.x, t = threadIdx.x;
  const int b = qb / 12, ht = qb % 12;
  float csp = 0.f;
  for (int c = 0; c < NCHUNK; ++c) csp += sp_cnt[b * NCHUNK + c];
  const float inv = 1.f / csp;
  #pragma unroll
  for (int k = 0; k < 3; ++k) {
    const int h = t + k * 256;
    float a = 0.f;
    for (int c = 0; c < NCHUNK; ++c)
      a += sp_part[((size_t)b * NCHUNK + c) * H + h];
    spL[h] = a * inv;
  }
  __syncthreads();
  const int hl = t & 63, dseg = t >> 6;
  const int h = ht * 64 + hl;
  const float* wp = W_attn + (size_t)(dseg * 192) * H + h;
  const float* sv = spL + dseg * 192;
  float acc = 0.f;
  #pragma unroll 4
  for (int i = 0; i < 192; ++i) acc += sv[i] * wp[(size_t)i * H];
  red[t] = acc;
  __syncthreads();
  if (t < 64)
    q[(size_t)b * H + ht * 64 + t] = red[t] + red[t + 64] + red[t + 128] + red[t + 192];
}

// ---------------------------------------------------------------------------
// K3: sim -> ragged softmax -> pooled.  Grid: B*NS = 128 blocks, 256 threads.
// [R2-validated]
// ---------------------------------------------------------------------------
__global__ __launch_bounds__(256)
void k_attn_pool(const float* __restrict__ row_cls, const float* __restrict__ q,
                 const int* __restrict__ extra_index, float* __restrict__ pooled) {
  const int blk = blockIdx.x;
  const int b = blk >> 3, n = blk & 7;
  const int t = threadIdx.x;
  const size_t base = ((size_t)b * S1 + n * M) * H;
  __shared__ float red[256];
  __shared__ float wgt[M];
  float qv[3];
  #pragma unroll
  for (int k = 0; k < 3; ++k) qv[k] = q[(size_t)b * H + t + k * 256];
  #pragma unroll
  for (int m = 0; m < M; ++m) {
    float p = 0.f;
    #pragma unroll
    for (int k = 0; k < 3; ++k) {
      const int h = t + k * 256;
      p += qv[k] * row_cls[base + (size_t)m * H + h];
    }
    red[t] = p;
    __syncthreads();
    for (int s = 128; s > 0; s >>= 1) { if (t < s) red[t] += red[t + s]; __syncthreads(); }
    if (t == 0) wgt[m] = red[0];
    __syncthreads();
  }
  if (t == 0) {
    const int vid = extra_index[b * NS + n];
    const float scale = 0.036084391824351615f;  // 1/sqrt(768)
    float x[M], mx = -1e30f;
    #pragma unroll
    for (int m = 0; m < M; ++m) {
      x[m] = (m < vid) ? wgt[m] * scale : -1e30f;
      mx = fmaxf(mx, x[m]);
    }
    float s = 0.f, e[M];
    #pragma unroll
    for (int m = 0; m < M; ++m) { e[m] = expf(x[m] - mx); s += e[m]; }
    #pragma unroll
    for (int m = 0; m < M; ++m) wgt[m] = e[m] / s;
  }
  __syncthreads();
  #pragma unroll
  for (int k = 0; k < 3; ++k) {
    const int h = t + k * 256;
    float acc = 0.f;
    #pragma unroll
    for (int m = 0; m < M; ++m) acc += wgt[m] * row_cls[base + (size_t)m * H + h];
    pooled[(size_t)blk * H + h] = acc;
  }
}

// ---------------------------------------------------------------------------
// K4: y[b,n,h] = pooled[b,n,:] . W_t[h,:] + b_t[h]  (float4, shared W load
// between the two n-accumulators).  Grid: B*12, 256 threads.  [R2-validated]
// ---------------------------------------------------------------------------
__global__ __launch_bounds__(256)
void k_transform(const float* __restrict__ pooled, const float* __restrict__ W_t,
                 const float* __restrict__ b_t, float* __restrict__ y) {
  const int blk = blockIdx.x;
  const int b = blk / 12, hc = blk % 12;
  const int t = threadIdx.x;
  __shared__ float pL[NS * H];  // 24 KiB
  for (int idx = t; idx < NS * H; idx += 256)
    pL[idx] = pooled[(size_t)b * NS * H + idx];
  __syncthreads();
  const int hl = t & 63;
  const int n0 = t >> 6;            // 0..3 (whole wave shares n -> LDS bcast)
  const int h = hc * 64 + hl;
  const float4* wr = (const float4*)(W_t + (size_t)h * H);
  const float4* pr0 = (const float4*)(pL + n0 * H);
  const float4* pr1 = (const float4*)(pL + (n0 + 4) * H);
  float acc0 = 0.f, acc1 = 0.f;
  #pragma unroll 4
  for (int d = 0; d < HV4; ++d) {
    float4 w = wr[d];
    float4 p0 = pr0[d], p1 = pr1[d];
    acc0 += w.x * p0.x + w.y * p0.y + w.z * p0.z + w.w * p0.w;
    acc1 += w.x * p1.x + w.y * p1.y + w.z * p1.z + w.w * p1.w;
  }
  const float bias = b_t[h];
  y[((size_t)b * NS + n0) * H + h] = acc0 + bias;
  y[((size_t)b * NS + n0 + 4) * H + h] = acc1 + bias;
}

// ---------------------------------------------------------------------------
// K5: sel combine + LayerNorm(gamma_s) fused with row-LN(gamma_t) + cosine
// score (cls_out never materialized). Grid: B blocks, 256 threads.
// [R3-validated]
// ---------------------------------------------------------------------------
__global__ __launch_bounds__(256)
void k_lnscore(const float* __restrict__ sel_part, const float* __restrict__ sel_cnt,
               const float* __restrict__ gamma_s, const float* __restrict__ beta_s,
               const float* __restrict__ yb, const float* __restrict__ gamma_t,
               const float* __restrict__ beta_t, float* __restrict__ out) {
  const int b = blockIdx.x, t = threadIdx.x;
  __shared__ float red[256];
  __shared__ float mv[2];
  // sel combine + LN
  float csel = 0.f;
  for (int c = 0; c < NCHUNK; ++c) csel += sel_cnt[b * NCHUNK + c];
  float selv[3];
  #pragma unroll
  for (int k = 0; k < 3; ++k) {
    const int h = t + k * 256;
    float s = 0.f;
    for (int c = 0; c < NCHUNK; ++c)
      s += sel_part[((size_t)b * NCHUNK + c) * H + h];
    selv[k] = s / csel;
  }
  red[t] = selv[0] + selv[1] + selv[2];
  __syncthreads();
  for (int s = 128; s > 0; s >>= 1) { if (t < s) red[t] += red[t + s]; __syncthreads(); }
  if (t == 0) mv[0] = red[0] / (float)H;
  __syncthreads();
  float mu = mv[0];
  float lv = 0.f;
  #pragma unroll
  for (int k = 0; k < 3; ++k) { float d = selv[k] - mu; lv += d * d; }
  red[t] = lv;
  __syncthreads();
  for (int s = 128; s > 0; s >>= 1) { if (t < s) red[t] += red[t + s]; __syncthreads(); }
  if (t == 0) mv[1] = red[0] / (float)H;
  __syncthreads();
  float rstd = rsqrtf(mv[1] + 1e-12f);
  float sl[3];
  #pragma unroll
  for (int k = 0; k < 3; ++k) {
    const int h = t + k * 256;
    sl[k] = (selv[k] - mu) * rstd * gamma_s[h] + beta_s[h];
  }
  __syncthreads();
  // per-row LN of y + S/SS accumulation
  float g[3], be[3];
  #pragma unroll
  for (int k = 0; k < 3; ++k) { g[k] = gamma_t[t + k * 256]; be[k] = beta_t[t + k * 256]; }
  float S[3] = {0.f, 0.f, 0.f}, SS[3] = {0.f, 0.f, 0.f};
  for (int n = 0; n < NS; ++n) {
    float v[3];
    #pragma unroll
    for (int k = 0; k < 3; ++k) v[k] = yb[((size_t)b * NS + n) * H + t + k * 256];
    red[t] = v[0] + v[1] + v[2];
    __syncthreads();
    for (int s = 128; s > 0; s >>= 1) { if (t < s) red[t] += red[t + s]; __syncthreads(); }
    if (t == 0) mv[0] = red[0] / (float)H;
    __syncthreads();
    const float mun = mv[0];
    float lvn = 0.f;
    #pragma unroll
    for (int k = 0; k < 3; ++k) { float d = v[k] - mun; lvn += d * d; }
    red[t] = lvn;
    __syncthreads();
    for (int s = 128; s > 0; s >>= 1) { if (t < s) red[t] += red[t + s]; __syncthreads(); }
    if (t == 0) mv[1] = red[0] / (float)H;
    __syncthreads();
    const float rstdn = rsqrtf(mv[1] + 1e-12f);
    #pragma unroll
    for (int k = 0; k < 3; ++k) {
      const float c = (v[k] - mun) * rstdn * g[k] + be[k];
      S[k] += c; SS[k] += c * c;
    }
    __syncthreads();
  }
  #pragma unroll
  for (int k = 0; k < 3; ++k) {
    const int h = t + k * 256;
    const float n1 = 2.8284271247461903f * fabsf(sl[k]);  // sqrt(8)*|sel|
    const float n2 = sqrtf(SS[k]);
    out[(size_t)b * H + h] = sl[k] * S[k] / (fmaxf(n1, 1e-8f) * fmaxf(n2, 1e-8f));
  }
}

// ---------------------------------------------------------------------------
extern "C" void kernel_launch(void* const* d_in, const int* in_sizes, int n_in,
                              void* d_out, int out_size, void* d_ws, size_t ws_size,
                              hipStream_t stream) {
  const float* hidden_states = (const float*)d_in[0];
  const float* sent_h1       = (const float*)d_in[1];
  const float* sent_h2       = (const float*)d_in[2];
  const int*   attention_mask= (const int*)  d_in[3];
  const float* expl_h1       = (const float*)d_in[4];
  const float* expl_h2       = (const float*)d_in[5];
  const int*   extra_am      = (const int*)  d_in[6];
  const int*   extra_index   = (const int*)  d_in[7];
  const int*   extra_start   = (const int*)  d_in[8];
  const int*   extra_end     = (const int*)  d_in[9];
  const float* W_attn        = (const float*)d_in[10];
  const float* W_t           = (const float*)d_in[11];
  const float* b_t           = (const float*)d_in[12];
  const float* gamma_t       = (const float*)d_in[13];
  const float* beta_t        = (const float*)d_in[14];
  const float* gamma_s       = (const float*)d_in[15];
  const float* beta_s        = (const float*)d_in[16];
  float* out = (float*)d_out;

  float* ws = (float*)d_ws;
  float* row_cls  = ws;                        // 512*768
  float* sp_part  = row_cls + 512 * H;         // 512*768
  float* sp_cnt   = sp_part + 512 * H;         // 512
  float* sel_part = sp_cnt + 512;              // 512*768
  float* sel_cnt  = sel_part + 512 * H;        // 512
  float* q        = sel_cnt + 512;             // 16*768
  float* pooled   = q + B * H;                 // 128*768
  float* yb       = pooled + B * NS * H;       // 128*768

  k_pool<<<1536, 192, 0, stream>>>(expl_h1, expl_h2, extra_am,
                                   sent_h1, sent_h2, attention_mask,
                                   hidden_states, extra_start, extra_end,
                                   row_cls, sp_part, sp_cnt, sel_part, sel_cnt);
  k_q<<<192, 256, 0, stream>>>(sp_part, sp_cnt, W_attn, q);
  k_attn_pool<<<B * NS, 256, 0, stream>>>(row_cls, q, extra_index, pooled);
  k_transform<<<B * 12, 256, 0, stream>>>(pooled, W_t, b_t, yb);
  k_lnscore<<<B, 256, 0, stream>>>(sel_part, sel_cnt, gamma_s, beta_s,
                                   yb, gamma_t, beta_t, out);
}

// Round 6
// 123.034 us; speedup vs baseline: 1.0474x; 1.0057x over previous
//
#include <hip/hip_runtime.h>
#include <math.h>

// Problem constants (fixed by setup_inputs)
#define B   16
#define L   512
#define H   768
#define HV4 192      // H/4 float4s per row
#define S1  32
#define S2  128
#define NS  8
#define M   4
#define CH  16       // L-chunk rows per partial block
#define NCHUNK 32    // L / CH

// ---------------------------------------------------------------------------
// K1 (fused): 1536 blocks, 384 threads (two 192-thread halves).
// Masks are {0,1} (jax randint(0,2)) so masked mean == mean over compacted
// rows; compaction is wave-parallel via ballot+popcount (no serial lane-0
// loop). Halves process even/odd compacted rows -> 2x in-flight loads/CU,
// combined through LDS at the end.
//   bid <  512 : row_cls mean over selected rows of expl_h1+expl_h2 (~200MB)
//   bid < 1024 : sent partial sums over 16-row chunks
//   else       : sel span partial sums over 16-row chunks
// R5->R6 fix: sel branch pair-unroll read row l+2 with guard l+1<hi (OOB by
// one row for even-length tails). Replaced with the simple stride-2 loop.
// ---------------------------------------------------------------------------
__global__ __launch_bounds__(384)
void k_pool(const float* __restrict__ e1, const float* __restrict__ e2,
            const int* __restrict__ am,
            const float* __restrict__ s1, const float* __restrict__ s2,
            const int* __restrict__ iam,
            const float* __restrict__ hs, const int* __restrict__ st_,
            const int* __restrict__ en_,
            float* __restrict__ row_cls,
            float* __restrict__ sp_part, float* __restrict__ sp_cnt,
            float* __restrict__ sel_part, float* __restrict__ sel_cnt) {
  const int bid = blockIdx.x;
  const int t = threadIdx.x;
  const int half = t / 192;       // wave-uniform (waves 0-2 vs 3-5)
  const int tt = t % 192;
  __shared__ int   idxL[S2];
  __shared__ int   cntS;
  __shared__ float4 pf[192];      // half-1 partials for the combine

  if (bid < 512) {
    const int i = bid;
    if (t < 64) {
      const int m0 = am[i * S2 + t];
      const int m1 = am[i * S2 + 64 + t];
      const unsigned long long b0 = __ballot(m0 != 0);
      const unsigned long long b1 = __ballot(m1 != 0);
      const int c0 = (int)__popcll(b0);
      if (m0) idxL[(int)__popcll(b0 & ((1ULL << t) - 1))] = t;
      if (m1) idxL[c0 + (int)__popcll(b1 & ((1ULL << t) - 1))] = 64 + t;
      if (t == 0) cntS = c0 + (int)__popcll(b1);
    }
    __syncthreads();
    const int cnt = cntS;
    const int cntH = (cnt + 1 - half) >> 1;   // half0 ceil, half1 floor
    const float4* p1 = (const float4*)e1 + (size_t)i * (S2 * HV4) + tt;
    const float4* p2 = (const float4*)e2 + (size_t)i * (S2 * HV4) + tt;
    float ax = 0.f, ay = 0.f, az = 0.f, aw = 0.f;
    int kk = 0;
    for (; kk + 3 < cntH; kk += 4) {
      const int j0 = idxL[2 * kk + half];
      const int j1 = idxL[2 * (kk + 1) + half];
      const int j2 = idxL[2 * (kk + 2) + half];
      const int j3 = idxL[2 * (kk + 3) + half];
      float4 a0 = p1[j0 * HV4], b0 = p2[j0 * HV4];
      float4 a1 = p1[j1 * HV4], b1 = p2[j1 * HV4];
      float4 a2 = p1[j2 * HV4], b2 = p2[j2 * HV4];
      float4 a3 = p1[j3 * HV4], b3 = p2[j3 * HV4];
      ax += (a0.x + b0.x) + (a1.x + b1.x) + (a2.x + b2.x) + (a3.x + b3.x);
      ay += (a0.y + b0.y) + (a1.y + b1.y) + (a2.y + b2.y) + (a3.y + b3.y);
      az += (a0.z + b0.z) + (a1.z + b1.z) + (a2.z + b2.z) + (a3.z + b3.z);
      aw += (a0.w + b0.w) + (a1.w + b1.w) + (a2.w + b2.w) + (a3.w + b3.w);
    }
    for (; kk < cntH; ++kk) {
      const int j = idxL[2 * kk + half];
      float4 a = p1[j * HV4], b = p2[j * HV4];
      ax += a.x + b.x; ay += a.y + b.y; az += a.z + b.z; aw += a.w + b.w;
    }
    if (half == 1) { float4 o; o.x = ax; o.y = ay; o.z = az; o.w = aw; pf[tt] = o; }
    __syncthreads();
    if (half == 0) {
      const float inv = 1.f / (float)cnt;
      float4 o = pf[tt];
      o.x = (ax + o.x) * inv; o.y = (ay + o.y) * inv;
      o.z = (az + o.z) * inv; o.w = (aw + o.w) * inv;
      ((float4*)row_cls)[(size_t)i * HV4 + tt] = o;
    }
  } else if (bid < 1024) {
    const int blk = bid - 512;
    const int b = blk >> 5, c = blk & 31;
    if (t < 64) {
      const int m = (t < CH) ? iam[b * L + c * CH + t] : 0;
      const unsigned long long bm = __ballot(m != 0);
      if (m) idxL[(int)__popcll(bm & ((1ULL << t) - 1))] = t;
      if (t == 0) { const int cc = (int)__popcll(bm); cntS = cc; sp_cnt[blk] = (float)cc; }
    }
    __syncthreads();
    const int cnt = cntS;
    const int cntH = (cnt + 1 - half) >> 1;
    const float4* p1 = (const float4*)s1 + ((size_t)b * L + c * CH) * HV4 + tt;
    const float4* p2 = (const float4*)s2 + ((size_t)b * L + c * CH) * HV4 + tt;
    float ax = 0.f, ay = 0.f, az = 0.f, aw = 0.f;
    int kk = 0;
    for (; kk + 1 < cntH; kk += 2) {
      const int l0 = idxL[2 * kk + half];
      const int l1 = idxL[2 * (kk + 1) + half];
      float4 a0 = p1[l0 * HV4], b0 = p2[l0 * HV4];
      float4 a1 = p1[l1 * HV4], b1 = p2[l1 * HV4];
      ax += (a0.x + b0.x) + (a1.x + b1.x);
      ay += (a0.y + b0.y) + (a1.y + b1.y);
      az += (a0.z + b0.z) + (a1.z + b1.z);
      aw += (a0.w + b0.w) + (a1.w + b1.w);
    }
    for (; kk < cntH; ++kk) {
      const int l = idxL[2 * kk + half];
      float4 a = p1[l * HV4], b = p2[l * HV4];
      ax += a.x + b.x; ay += a.y + b.y; az += a.z + b.z; aw += a.w + b.w;
    }
    if (half == 1) { float4 o; o.x = ax; o.y = ay; o.z = az; o.w = aw; pf[tt] = o; }
    __syncthreads();
    if (half == 0) {
      float4 o = pf[tt];
      o.x += ax; o.y += ay; o.z += az; o.w += aw;
      ((float4*)sp_part)[(size_t)blk * HV4 + tt] = o;
    }
  } else {
    const int blk = bid - 1024;
    const int b = blk >> 5, c = blk & 31;
    const int st = st_[b], en = en_[b];
    const int lo = st > c * CH ? st : c * CH;
    const int hi = en < c * CH + CH ? en : c * CH + CH;
    const float4* p = (const float4*)hs + (size_t)b * L * HV4 + tt;
    float ax = 0.f, ay = 0.f, az = 0.f, aw = 0.f;
    for (int l = lo + half; l < hi; l += 2) {   // this half's rows, in-bounds
      float4 a0 = p[l * HV4];
      ax += a0.x; ay += a0.y; az += a0.z; aw += a0.w;
    }
    if (half == 1) { float4 o; o.x = ax; o.y = ay; o.z = az; o.w = aw; pf[tt] = o; }
    __syncthreads();
    if (half == 0) {
      float4 o = pf[tt];
      o.x += ax; o.y += ay; o.z += az; o.w += aw;
      ((float4*)sel_part)[(size_t)blk * HV4 + tt] = o;
      if (tt == 0) sel_cnt[blk] = (float)(hi > lo ? hi - lo : 0);
    }
  }
}

// ---------------------------------------------------------------------------
// K2: q[b, 64-h tile] = sp[b,:] @ W_attn. Grid 192 blocks (b x 12 h-tiles),
// 256 threads, d split 4-way per block.  [R4-identical]
// ---------------------------------------------------------------------------
__global__ __launch_bounds__(256)
void k_q(const float* __restrict__ sp_part, const float* __restrict__ sp_cnt,
         const float* __restrict__ W_attn, float* __restrict__ q) {
  __shared__ float spL[H];
  __shared__ float red[256];
  const int qb = blockIdx.x, t = threadIdx.x;
  const int b = qb / 12, ht = qb % 12;
  float csp = 0.f;
  for (int c = 0; c < NCHUNK; ++c) csp += sp_cnt[b * NCHUNK + c];
  const float inv = 1.f / csp;
  #pragma unroll
  for (int k = 0; k < 3; ++k) {
    const int h = t + k * 256;
    float a = 0.f;
    for (int c = 0; c < NCHUNK; ++c)
      a += sp_part[((size_t)b * NCHUNK + c) * H + h];
    spL[h] = a * inv;
  }
  __syncthreads();
  const int hl = t & 63, dseg = t >> 6;
  const int h = ht * 64 + hl;
  const float* wp = W_attn + (size_t)(dseg * 192) * H + h;
  const float* sv = spL + dseg * 192;
  float acc = 0.f;
  #pragma unroll 4
  for (int i = 0; i < 192; ++i) acc += sv[i] * wp[(size_t)i * H];
  red[t] = acc;
  __syncthreads();
  if (t < 64)
    q[(size_t)b * H + ht * 64 + t] = red[t] + red[t + 64] + red[t + 128] + red[t + 192];
}

// ---------------------------------------------------------------------------
// K3: sim -> ragged softmax -> pooled.  Grid: B*NS = 128 blocks, 256 threads.
// [R4-identical]
// ---------------------------------------------------------------------------
__global__ __launch_bounds__(256)
void k_attn_pool(const float* __restrict__ row_cls, const float* __restrict__ q,
                 const int* __restrict__ extra_index, float* __restrict__ pooled) {
  const int blk = blockIdx.x;
  const int b = blk >> 3, n = blk & 7;
  const int t = threadIdx.x;
  const size_t base = ((size_t)b * S1 + n * M) * H;
  __shared__ float red[256];
  __shared__ float wgt[M];
  float qv[3];
  #pragma unroll
  for (int k = 0; k < 3; ++k) qv[k] = q[(size_t)b * H + t + k * 256];
  #pragma unroll
  for (int m = 0; m < M; ++m) {
    float p = 0.f;
    #pragma unroll
    for (int k = 0; k < 3; ++k) {
      const int h = t + k * 256;
      p += qv[k] * row_cls[base + (size_t)m * H + h];
    }
    red[t] = p;
    __syncthreads();
    for (int s = 128; s > 0; s >>= 1) { if (t < s) red[t] += red[t + s]; __syncthreads(); }
    if (t == 0) wgt[m] = red[0];
    __syncthreads();
  }
  if (t == 0) {
    const int vid = extra_index[b * NS + n];
    const float scale = 0.036084391824351615f;  // 1/sqrt(768)
    float x[M], mx = -1e30f;
    #pragma unroll
    for (int m = 0; m < M; ++m) {
      x[m] = (m < vid) ? wgt[m] * scale : -1e30f;
      mx = fmaxf(mx, x[m]);
    }
    float s = 0.f, e[M];
    #pragma unroll
    for (int m = 0; m < M; ++m) { e[m] = expf(x[m] - mx); s += e[m]; }
    #pragma unroll
    for (int m = 0; m < M; ++m) wgt[m] = e[m] / s;
  }
  __syncthreads();
  #pragma unroll
  for (int k = 0; k < 3; ++k) {
    const int h = t + k * 256;
    float acc = 0.f;
    #pragma unroll
    for (int m = 0; m < M; ++m) acc += wgt[m] * row_cls[base + (size_t)m * H + h];
    pooled[(size_t)blk * H + h] = acc;
  }
}

// ---------------------------------------------------------------------------
// K4: y[b,n,h] = pooled[b,n,:] . W_t[h,:] + b_t[h]  (float4, shared W load
// between the two n-accumulators).  Grid: B*12, 256 threads.  [R4-identical]
// ---------------------------------------------------------------------------
__global__ __launch_bounds__(256)
void k_transform(const float* __restrict__ pooled, const float* __restrict__ W_t,
                 const float* __restrict__ b_t, float* __restrict__ y) {
  const int blk = blockIdx.x;
  const int b = blk / 12, hc = blk % 12;
  const int t = threadIdx.x;
  __shared__ float pL[NS * H];  // 24 KiB
  for (int idx = t; idx < NS * H; idx += 256)
    pL[idx] = pooled[(size_t)b * NS * H + idx];
  __syncthreads();
  const int hl = t & 63;
  const int n0 = t >> 6;            // 0..3 (whole wave shares n -> LDS bcast)
  const int h = hc * 64 + hl;
  const float4* wr = (const float4*)(W_t + (size_t)h * H);
  const float4* pr0 = (const float4*)(pL + n0 * H);
  const float4* pr1 = (const float4*)(pL + (n0 + 4) * H);
  float acc0 = 0.f, acc1 = 0.f;
  #pragma unroll 4
  for (int d = 0; d < HV4; ++d) {
    float4 w = wr[d];
    float4 p0 = pr0[d], p1 = pr1[d];
    acc0 += w.x * p0.x + w.y * p0.y + w.z * p0.z + w.w * p0.w;
    acc1 += w.x * p1.x + w.y * p1.y + w.z * p1.z + w.w * p1.w;
  }
  const float bias = b_t[h];
  y[((size_t)b * NS + n0) * H + h] = acc0 + bias;
  y[((size_t)b * NS + n0 + 4) * H + h] = acc1 + bias;
}

// ---------------------------------------------------------------------------
// K5: sel combine + LayerNorm(gamma_s) fused with row-LN(gamma_t) + cosine
// score (cls_out never materialized). Grid: B blocks, 256 threads.
// [R4-identical]
// ---------------------------------------------------------------------------
__global__ __launch_bounds__(256)
void k_lnscore(const float* __restrict__ sel_part, const float* __restrict__ sel_cnt,
               const float* __restrict__ gamma_s, const float* __restrict__ beta_s,
               const float* __restrict__ yb, const float* __restrict__ gamma_t,
               const float* __restrict__ beta_t, float* __restrict__ out) {
  const int b = blockIdx.x, t = threadIdx.x;
  __shared__ float red[256];
  __shared__ float mv[2];
  // sel combine + LN
  float csel = 0.f;
  for (int c = 0; c < NCHUNK; ++c) csel += sel_cnt[b * NCHUNK + c];
  float selv[3];
  #pragma unroll
  for (int k = 0; k < 3; ++k) {
    const int h = t + k * 256;
    float s = 0.f;
    for (int c = 0; c < NCHUNK; ++c)
      s += sel_part[((size_t)b * NCHUNK + c) * H + h];
    selv[k] = s / csel;
  }
  red[t] = selv[0] + selv[1] + selv[2];
  __syncthreads();
  for (int s = 128; s > 0; s >>= 1) { if (t < s) red[t] += red[t + s]; __syncthreads(); }
  if (t == 0) mv[0] = red[0] / (float)H;
  __syncthreads();
  float mu = mv[0];
  float lv = 0.f;
  #pragma unroll
  for (int k = 0; k < 3; ++k) { float d = selv[k] - mu; lv += d * d; }
  red[t] = lv;
  __syncthreads();
  for (int s = 128; s > 0; s >>= 1) { if (t < s) red[t] += red[t + s]; __syncthreads(); }
  if (t == 0) mv[1] = red[0] / (float)H;
  __syncthreads();
  float rstd = rsqrtf(mv[1] + 1e-12f);
  float sl[3];
  #pragma unroll
  for (int k = 0; k < 3; ++k) {
    const int h = t + k * 256;
    sl[k] = (selv[k] - mu) * rstd * gamma_s[h] + beta_s[h];
  }
  __syncthreads();
  // per-row LN of y + S/SS accumulation
  float g[3], be[3];
  #pragma unroll
  for (int k = 0; k < 3; ++k) { g[k] = gamma_t[t + k * 256]; be[k] = beta_t[t + k * 256]; }
  float S[3] = {0.f, 0.f, 0.f}, SS[3] = {0.f, 0.f, 0.f};
  for (int n = 0; n < NS; ++n) {
    float v[3];
    #pragma unroll
    for (int k = 0; k < 3; ++k) v[k] = yb[((size_t)b * NS + n) * H + t + k * 256];
    red[t] = v[0] + v[1] + v[2];
    __syncthreads();
    for (int s = 128; s > 0; s >>= 1) { if (t < s) red[t] += red[t + s]; __syncthreads(); }
    if (t == 0) mv[0] = red[0] / (float)H;
    __syncthreads();
    const float mun = mv[0];
    float lvn = 0.f;
    #pragma unroll
    for (int k = 0; k < 3; ++k) { float d = v[k] - mun; lvn += d * d; }
    red[t] = lvn;
    __syncthreads();
    for (int s = 128; s > 0; s >>= 1) { if (t < s) red[t] += red[t + s]; __syncthreads(); }
    if (t == 0) mv[1] = red[0] / (float)H;
    __syncthreads();
    const float rstdn = rsqrtf(mv[1] + 1e-12f);
    #pragma unroll
    for (int k = 0; k < 3; ++k) {
      const float c = (v[k] - mun) * rstdn * g[k] + be[k];
      S[k] += c; SS[k] += c * c;
    }
    __syncthreads();
  }
  #pragma unroll
  for (int k = 0; k < 3; ++k) {
    const int h = t + k * 256;
    const float n1 = 2.8284271247461903f * fabsf(sl[k]);  // sqrt(8)*|sel|
    const float n2 = sqrtf(SS[k]);
    out[(size_t)b * H + h] = sl[k] * S[k] / (fmaxf(n1, 1e-8f) * fmaxf(n2, 1e-8f));
  }
}

// ---------------------------------------------------------------------------
extern "C" void kernel_launch(void* const* d_in, const int* in_sizes, int n_in,
                              void* d_out, int out_size, void* d_ws, size_t ws_size,
                              hipStream_t stream) {
  const float* hidden_states = (const float*)d_in[0];
  const float* sent_h1       = (const float*)d_in[1];
  const float* sent_h2       = (const float*)d_in[2];
  const int*   attention_mask= (const int*)  d_in[3];
  const float* expl_h1       = (const float*)d_in[4];
  const float* expl_h2       = (const float*)d_in[5];
  const int*   extra_am      = (const int*)  d_in[6];
  const int*   extra_index   = (const int*)  d_in[7];
  const int*   extra_start   = (const int*)  d_in[8];
  const int*   extra_end     = (const int*)  d_in[9];
  const float* W_attn        = (const float*)d_in[10];
  const float* W_t           = (const float*)d_in[11];
  const float* b_t           = (const float*)d_in[12];
  const float* gamma_t       = (const float*)d_in[13];
  const float* beta_t        = (const float*)d_in[14];
  const float* gamma_s       = (const float*)d_in[15];
  const float* beta_s        = (const float*)d_in[16];
  float* out = (float*)d_out;

  float* ws = (float*)d_ws;
  float* row_cls  = ws;                        // 512*768
  float* sp_part  = row_cls + 512 * H;         // 512*768
  float* sp_cnt   = sp_part + 512 * H;         // 512
  float* sel_part = sp_cnt + 512;              // 512*768
  float* sel_cnt  = sel_part + 512 * H;        // 512
  float* q        = sel_cnt + 512;             // 16*768
  float* pooled   = q + B * H;                 // 128*768
  float* yb       = pooled + B * NS * H;       // 128*768

  k_pool<<<1536, 384, 0, stream>>>(expl_h1, expl_h2, extra_am,
                                   sent_h1, sent_h2, attention_mask,
                                   hidden_states, extra_start, extra_end,
                                   row_cls, sp_part, sp_cnt, sel_part, sel_cnt);
  k_q<<<192, 256, 0, stream>>>(sp_part, sp_cnt, W_attn, q);
  k_attn_pool<<<B * NS, 256, 0, stream>>>(row_cls, q, extra_index, pooled);
  k_transform<<<B * 12, 256, 0, stream>>>(pooled, W_t, b_t, yb);
  k_lnscore<<<B, 256, 0, stream>>>(sel_part, sel_cnt, gamma_s, beta_s,
                                   yb, gamma_t, beta_t, out);
}

// Round 7
// 104.432 us; speedup vs baseline: 1.2340x; 1.1781x over previous
//
#include <hip/hip_runtime.h>
#include <math.h>

// Problem constants (fixed by setup_inputs)
#define B   16
#define L   512
#define H   768
#define HV4 192      // H/4 float4s per row
#define S1  32
#define S2  128
#define NS  8
#define M   4
#define CH  16       // L-chunk rows per partial block
#define NCHUNK 32    // L / CH

// ---------------------------------------------------------------------------
// K1 (fused): 1536 blocks, 384 threads (two 192-thread halves). [R6-validated]
//   bid <  512 : row_cls mean over ballot-compacted rows of expl_h1+expl_h2
//   bid < 1024 : sent partial sums over 16-row chunks
//   else       : sel span partial sums over 16-row chunks
// ---------------------------------------------------------------------------
__global__ __launch_bounds__(384)
void k_pool(const float* __restrict__ e1, const float* __restrict__ e2,
            const int* __restrict__ am,
            const float* __restrict__ s1, const float* __restrict__ s2,
            const int* __restrict__ iam,
            const float* __restrict__ hs, const int* __restrict__ st_,
            const int* __restrict__ en_,
            float* __restrict__ row_cls,
            float* __restrict__ sp_part, float* __restrict__ sp_cnt,
            float* __restrict__ sel_part, float* __restrict__ sel_cnt) {
  const int bid = blockIdx.x;
  const int t = threadIdx.x;
  const int half = t / 192;       // wave-uniform (waves 0-2 vs 3-5)
  const int tt = t % 192;
  __shared__ int   idxL[S2];
  __shared__ int   cntS;
  __shared__ float4 pf[192];      // half-1 partials for the combine

  if (bid < 512) {
    const int i = bid;
    if (t < 64) {
      const int m0 = am[i * S2 + t];
      const int m1 = am[i * S2 + 64 + t];
      const unsigned long long b0 = __ballot(m0 != 0);
      const unsigned long long b1 = __ballot(m1 != 0);
      const int c0 = (int)__popcll(b0);
      if (m0) idxL[(int)__popcll(b0 & ((1ULL << t) - 1))] = t;
      if (m1) idxL[c0 + (int)__popcll(b1 & ((1ULL << t) - 1))] = 64 + t;
      if (t == 0) cntS = c0 + (int)__popcll(b1);
    }
    __syncthreads();
    const int cnt = cntS;
    const int cntH = (cnt + 1 - half) >> 1;   // half0 ceil, half1 floor
    const float4* p1 = (const float4*)e1 + (size_t)i * (S2 * HV4) + tt;
    const float4* p2 = (const float4*)e2 + (size_t)i * (S2 * HV4) + tt;
    float ax = 0.f, ay = 0.f, az = 0.f, aw = 0.f;
    int kk = 0;
    for (; kk + 3 < cntH; kk += 4) {
      const int j0 = idxL[2 * kk + half];
      const int j1 = idxL[2 * (kk + 1) + half];
      const int j2 = idxL[2 * (kk + 2) + half];
      const int j3 = idxL[2 * (kk + 3) + half];
      float4 a0 = p1[j0 * HV4], b0 = p2[j0 * HV4];
      float4 a1 = p1[j1 * HV4], b1 = p2[j1 * HV4];
      float4 a2 = p1[j2 * HV4], b2 = p2[j2 * HV4];
      float4 a3 = p1[j3 * HV4], b3 = p2[j3 * HV4];
      ax += (a0.x + b0.x) + (a1.x + b1.x) + (a2.x + b2.x) + (a3.x + b3.x);
      ay += (a0.y + b0.y) + (a1.y + b1.y) + (a2.y + b2.y) + (a3.y + b3.y);
      az += (a0.z + b0.z) + (a1.z + b1.z) + (a2.z + b2.z) + (a3.z + b3.z);
      aw += (a0.w + b0.w) + (a1.w + b1.w) + (a2.w + b2.w) + (a3.w + b3.w);
    }
    for (; kk < cntH; ++kk) {
      const int j = idxL[2 * kk + half];
      float4 a = p1[j * HV4], b = p2[j * HV4];
      ax += a.x + b.x; ay += a.y + b.y; az += a.z + b.z; aw += a.w + b.w;
    }
    if (half == 1) { float4 o; o.x = ax; o.y = ay; o.z = az; o.w = aw; pf[tt] = o; }
    __syncthreads();
    if (half == 0) {
      const float inv = 1.f / (float)cnt;
      float4 o = pf[tt];
      o.x = (ax + o.x) * inv; o.y = (ay + o.y) * inv;
      o.z = (az + o.z) * inv; o.w = (aw + o.w) * inv;
      ((float4*)row_cls)[(size_t)i * HV4 + tt] = o;
    }
  } else if (bid < 1024) {
    const int blk = bid - 512;
    const int b = blk >> 5, c = blk & 31;
    if (t < 64) {
      const int m = (t < CH) ? iam[b * L + c * CH + t] : 0;
      const unsigned long long bm = __ballot(m != 0);
      if (m) idxL[(int)__popcll(bm & ((1ULL << t) - 1))] = t;
      if (t == 0) { const int cc = (int)__popcll(bm); cntS = cc; sp_cnt[blk] = (float)cc; }
    }
    __syncthreads();
    const int cnt = cntS;
    const int cntH = (cnt + 1 - half) >> 1;
    const float4* p1 = (const float4*)s1 + ((size_t)b * L + c * CH) * HV4 + tt;
    const float4* p2 = (const float4*)s2 + ((size_t)b * L + c * CH) * HV4 + tt;
    float ax = 0.f, ay = 0.f, az = 0.f, aw = 0.f;
    int kk = 0;
    for (; kk + 1 < cntH; kk += 2) {
      const int l0 = idxL[2 * kk + half];
      const int l1 = idxL[2 * (kk + 1) + half];
      float4 a0 = p1[l0 * HV4], b0 = p2[l0 * HV4];
      float4 a1 = p1[l1 * HV4], b1 = p2[l1 * HV4];
      ax += (a0.x + b0.x) + (a1.x + b1.x);
      ay += (a0.y + b0.y) + (a1.y + b1.y);
      az += (a0.z + b0.z) + (a1.z + b1.z);
      aw += (a0.w + b0.w) + (a1.w + b1.w);
    }
    for (; kk < cntH; ++kk) {
      const int l = idxL[2 * kk + half];
      float4 a = p1[l * HV4], b = p2[l * HV4];
      ax += a.x + b.x; ay += a.y + b.y; az += a.z + b.z; aw += a.w + b.w;
    }
    if (half == 1) { float4 o; o.x = ax; o.y = ay; o.z = az; o.w = aw; pf[tt] = o; }
    __syncthreads();
    if (half == 0) {
      float4 o = pf[tt];
      o.x += ax; o.y += ay; o.z += az; o.w += aw;
      ((float4*)sp_part)[(size_t)blk * HV4 + tt] = o;
    }
  } else {
    const int blk = bid - 1024;
    const int b = blk >> 5, c = blk & 31;
    const int st = st_[b], en = en_[b];
    const int lo = st > c * CH ? st : c * CH;
    const int hi = en < c * CH + CH ? en : c * CH + CH;
    const float4* p = (const float4*)hs + (size_t)b * L * HV4 + tt;
    float ax = 0.f, ay = 0.f, az = 0.f, aw = 0.f;
    for (int l = lo + half; l < hi; l += 2) {   // this half's rows, in-bounds
      float4 a0 = p[l * HV4];
      ax += a0.x; ay += a0.y; az += a0.z; aw += a0.w;
    }
    if (half == 1) { float4 o; o.x = ax; o.y = ay; o.z = az; o.w = aw; pf[tt] = o; }
    __syncthreads();
    if (half == 0) {
      float4 o = pf[tt];
      o.x += ax; o.y += ay; o.z += az; o.w += aw;
      ((float4*)sel_part)[(size_t)blk * HV4 + tt] = o;
      if (tt == 0) sel_cnt[blk] = (float)(hi > lo ? hi - lo : 0);
    }
  }
}

// ---------------------------------------------------------------------------
// K2 (fused, R2 placement): grid 16 + 192 = 208 blocks, 256 threads.
//   bid < 16 : sel combine + LayerNorm(gamma_s) -> sel_ln.  Single-pass
//              sum/sumsq + shfl wave-reduce: 1 barrier (was 16 tree steps).
//   else     : q[b, 64-h tile] = sp[b,:] @ W_attn (d split 4-way).
// ---------------------------------------------------------------------------
__global__ __launch_bounds__(256)
void k_mid(const float* __restrict__ sp_part, const float* __restrict__ sp_cnt,
           const float* __restrict__ sel_part, const float* __restrict__ sel_cnt,
           const float* __restrict__ W_attn,
           const float* __restrict__ gamma_s, const float* __restrict__ beta_s,
           float* __restrict__ sel_ln, float* __restrict__ q) {
  __shared__ float spL[H];
  __shared__ float red[256];
  const int bid = blockIdx.x, t = threadIdx.x;
  const int lane = t & 63, w = t >> 6;
  if (bid < B) {
    const int b = bid;
    float csel = 0.f;
    for (int c = 0; c < NCHUNK; ++c) csel += sel_cnt[b * NCHUNK + c];
    const float invc = 1.f / csel;
    float selv[3];
    #pragma unroll
    for (int k = 0; k < 3; ++k) {
      const int h = t + k * 256;
      float s = 0.f;
      for (int c = 0; c < NCHUNK; ++c)
        s += sel_part[((size_t)b * NCHUNK + c) * H + h];
      selv[k] = s * invc;
    }
    float s = selv[0] + selv[1] + selv[2];
    float ss = selv[0] * selv[0] + selv[1] * selv[1] + selv[2] * selv[2];
    #pragma unroll
    for (int off = 32; off > 0; off >>= 1) {
      s += __shfl_down(s, off);
      ss += __shfl_down(ss, off);
    }
    if (lane == 0) { red[w] = s; red[4 + w] = ss; }
    __syncthreads();
    const float S = red[0] + red[1] + red[2] + red[3];
    const float SS = red[4] + red[5] + red[6] + red[7];
    const float mu = S / (float)H;
    const float var = SS / (float)H - mu * mu;
    const float rstd = rsqrtf(var + 1e-12f);
    #pragma unroll
    for (int k = 0; k < 3; ++k) {
      const int h = t + k * 256;
      sel_ln[(size_t)b * H + h] = (selv[k] - mu) * rstd * gamma_s[h] + beta_s[h];
    }
  } else {
    const int qb = bid - B;             // 0..191
    const int b = qb / 12, ht = qb % 12;
    float csp = 0.f;
    for (int c = 0; c < NCHUNK; ++c) csp += sp_cnt[b * NCHUNK + c];
    const float inv = 1.f / csp;
    #pragma unroll
    for (int k = 0; k < 3; ++k) {
      const int h = t + k * 256;
      float a = 0.f;
      for (int c = 0; c < NCHUNK; ++c)
        a += sp_part[((size_t)b * NCHUNK + c) * H + h];
      spL[h] = a * inv;
    }
    __syncthreads();
    const int hl = t & 63, dseg = t >> 6;
    const int h = ht * 64 + hl;
    const float* wp = W_attn + (size_t)(dseg * 192) * H + h;
    const float* sv = spL + dseg * 192;
    float acc = 0.f;
    #pragma unroll 4
    for (int i = 0; i < 192; ++i) acc += sv[i] * wp[(size_t)i * H];
    red[t] = acc;
    __syncthreads();
    if (t < 64)
      q[(size_t)b * H + ht * 64 + t] = red[t] + red[t + 64] + red[t + 128] + red[t + 192];
  }
}

// ---------------------------------------------------------------------------
// K3: sim -> ragged softmax -> pooled.  Grid: B*NS = 128 blocks, 256 threads.
// Shfl wave-reduce for the 4 sims: 2 barriers total (was ~65).
// ---------------------------------------------------------------------------
__global__ __launch_bounds__(256)
void k_attn_pool(const float* __restrict__ row_cls, const float* __restrict__ q,
                 const int* __restrict__ extra_index, float* __restrict__ pooled) {
  const int blk = blockIdx.x;
  const int b = blk >> 3, n = blk & 7;
  const int t = threadIdx.x;
  const int lane = t & 63, w = t >> 6;
  const size_t base = ((size_t)b * S1 + n * M) * H;
  __shared__ float wred[M * 4];
  __shared__ float wgt[M];
  float qv[3];
  #pragma unroll
  for (int k = 0; k < 3; ++k) qv[k] = q[(size_t)b * H + t + k * 256];
  float p[M];
  #pragma unroll
  for (int m = 0; m < M; ++m) {
    float a = 0.f;
    #pragma unroll
    for (int k = 0; k < 3; ++k) {
      const int h = t + k * 256;
      a += qv[k] * row_cls[base + (size_t)m * H + h];
    }
    p[m] = a;
  }
  #pragma unroll
  for (int off = 32; off > 0; off >>= 1) {
    #pragma unroll
    for (int m = 0; m < M; ++m) p[m] += __shfl_down(p[m], off);
  }
  if (lane == 0) {
    #pragma unroll
    for (int m = 0; m < M; ++m) wred[m * 4 + w] = p[m];
  }
  __syncthreads();
  if (t == 0) {
    const int vid = extra_index[b * NS + n];
    const float scale = 0.036084391824351615f;  // 1/sqrt(768)
    float x[M], mx = -1e30f;
    #pragma unroll
    for (int m = 0; m < M; ++m) {
      const float sim = (wred[m * 4] + wred[m * 4 + 1] + wred[m * 4 + 2] + wred[m * 4 + 3]) * scale;
      x[m] = (m < vid) ? sim : -1e30f;
      mx = fmaxf(mx, x[m]);
    }
    float s = 0.f, e[M];
    #pragma unroll
    for (int m = 0; m < M; ++m) { e[m] = expf(x[m] - mx); s += e[m]; }
    #pragma unroll
    for (int m = 0; m < M; ++m) wgt[m] = e[m] / s;
  }
  __syncthreads();
  #pragma unroll
  for (int k = 0; k < 3; ++k) {
    const int h = t + k * 256;
    float acc = 0.f;
    #pragma unroll
    for (int m = 0; m < M; ++m) acc += wgt[m] * row_cls[base + (size_t)m * H + h];
    pooled[(size_t)blk * H + h] = acc;
  }
}

// ---------------------------------------------------------------------------
// K4: y[b,n,h] = pooled[b,n,:] . W_t[h,:] + b_t[h]  (float4, shared W load
// between the two n-accumulators).  Grid: B*12, 256 threads.  [R2-identical]
// ---------------------------------------------------------------------------
__global__ __launch_bounds__(256)
void k_transform(const float* __restrict__ pooled, const float* __restrict__ W_t,
                 const float* __restrict__ b_t, float* __restrict__ y) {
  const int blk = blockIdx.x;
  const int b = blk / 12, hc = blk % 12;
  const int t = threadIdx.x;
  __shared__ float pL[NS * H];  // 24 KiB
  for (int idx = t; idx < NS * H; idx += 256)
    pL[idx] = pooled[(size_t)b * NS * H + idx];
  __syncthreads();
  const int hl = t & 63;
  const int n0 = t >> 6;            // 0..3 (whole wave shares n -> LDS bcast)
  const int h = hc * 64 + hl;
  const float4* wr = (const float4*)(W_t + (size_t)h * H);
  const float4* pr0 = (const float4*)(pL + n0 * H);
  const float4* pr1 = (const float4*)(pL + (n0 + 4) * H);
  float acc0 = 0.f, acc1 = 0.f;
  #pragma unroll 4
  for (int d = 0; d < HV4; ++d) {
    float4 w = wr[d];
    float4 p0 = pr0[d], p1 = pr1[d];
    acc0 += w.x * p0.x + w.y * p0.y + w.z * p0.z + w.w * p0.w;
    acc1 += w.x * p1.x + w.y * p1.y + w.z * p1.z + w.w * p1.w;
  }
  const float bias = b_t[h];
  y[((size_t)b * NS + n0) * H + h] = acc0 + bias;
  y[((size_t)b * NS + n0 + 4) * H + h] = acc1 + bias;
}

// ---------------------------------------------------------------------------
// K5: fused row-LayerNorm + cosine score (cls_out never materialized).
// Single-pass sum/sumsq per row, per-row LDS slots, ONE barrier total
// (was ~130).  Grid: B blocks, 256 threads.
// ---------------------------------------------------------------------------
__global__ __launch_bounds__(256)
void k_lnscore(const float* __restrict__ yb, const float* __restrict__ gamma,
               const float* __restrict__ beta, const float* __restrict__ sel_ln,
               float* __restrict__ out) {
  const int b = blockIdx.x, t = threadIdx.x;
  const int lane = t & 63, w = t >> 6;
  __shared__ float redS[NS * 4];
  __shared__ float redQ[NS * 4];
  float v[NS][3];
  for (int n = 0; n < NS; ++n) {
    float s = 0.f, ss = 0.f;
    #pragma unroll
    for (int k = 0; k < 3; ++k) {
      const float x = yb[((size_t)b * NS + n) * H + t + k * 256];
      v[n][k] = x; s += x; ss += x * x;
    }
    #pragma unroll
    for (int off = 32; off > 0; off >>= 1) {
      s += __shfl_down(s, off);
      ss += __shfl_down(ss, off);
    }
    if (lane == 0) { redS[n * 4 + w] = s; redQ[n * 4 + w] = ss; }
  }
  __syncthreads();
  float g[3], be[3];
  #pragma unroll
  for (int k = 0; k < 3; ++k) { g[k] = gamma[t + k * 256]; be[k] = beta[t + k * 256]; }
  float S[3] = {0.f, 0.f, 0.f}, SS[3] = {0.f, 0.f, 0.f};
  for (int n = 0; n < NS; ++n) {
    const float Sn = redS[n * 4] + redS[n * 4 + 1] + redS[n * 4 + 2] + redS[n * 4 + 3];
    const float Qn = redQ[n * 4] + redQ[n * 4 + 1] + redQ[n * 4 + 2] + redQ[n * 4 + 3];
    const float mu = Sn / (float)H;
    const float var = Qn / (float)H - mu * mu;
    const float rstd = rsqrtf(var + 1e-12f);
    #pragma unroll
    for (int k = 0; k < 3; ++k) {
      const float c = (v[n][k] - mu) * rstd * g[k] + be[k];
      S[k] += c; SS[k] += c * c;
    }
  }
  #pragma unroll
  for (int k = 0; k < 3; ++k) {
    const int h = t + k * 256;
    const float sl = sel_ln[(size_t)b * H + h];
    const float n1 = 2.8284271247461903f * fabsf(sl);  // sqrt(8)*|sel|
    const float n2 = sqrtf(SS[k]);
    out[(size_t)b * H + h] = sl * S[k] / (fmaxf(n1, 1e-8f) * fmaxf(n2, 1e-8f));
  }
}

// ---------------------------------------------------------------------------
extern "C" void kernel_launch(void* const* d_in, const int* in_sizes, int n_in,
                              void* d_out, int out_size, void* d_ws, size_t ws_size,
                              hipStream_t stream) {
  const float* hidden_states = (const float*)d_in[0];
  const float* sent_h1       = (const float*)d_in[1];
  const float* sent_h2       = (const float*)d_in[2];
  const int*   attention_mask= (const int*)  d_in[3];
  const float* expl_h1       = (const float*)d_in[4];
  const float* expl_h2       = (const float*)d_in[5];
  const int*   extra_am      = (const int*)  d_in[6];
  const int*   extra_index   = (const int*)  d_in[7];
  const int*   extra_start   = (const int*)  d_in[8];
  const int*   extra_end     = (const int*)  d_in[9];
  const float* W_attn        = (const float*)d_in[10];
  const float* W_t           = (const float*)d_in[11];
  const float* b_t           = (const float*)d_in[12];
  const float* gamma_t       = (const float*)d_in[13];
  const float* beta_t        = (const float*)d_in[14];
  const float* gamma_s       = (const float*)d_in[15];
  const float* beta_s        = (const float*)d_in[16];
  float* out = (float*)d_out;

  float* ws = (float*)d_ws;
  float* row_cls  = ws;                        // 512*768
  float* sp_part  = row_cls + 512 * H;         // 512*768
  float* sp_cnt   = sp_part + 512 * H;         // 512
  float* sel_part = sp_cnt + 512;              // 512*768
  float* sel_cnt  = sel_part + 512 * H;        // 512
  float* sel_ln   = sel_cnt + 512;             // 16*768
  float* q        = sel_ln + B * H;            // 16*768
  float* pooled   = q + B * H;                 // 128*768
  float* yb       = pooled + B * NS * H;       // 128*768

  k_pool<<<1536, 384, 0, stream>>>(expl_h1, expl_h2, extra_am,
                                   sent_h1, sent_h2, attention_mask,
                                   hidden_states, extra_start, extra_end,
                                   row_cls, sp_part, sp_cnt, sel_part, sel_cnt);
  k_mid<<<B + 192, 256, 0, stream>>>(sp_part, sp_cnt, sel_part, sel_cnt, W_attn,
                                     gamma_s, beta_s, sel_ln, q);
  k_attn_pool<<<B * NS, 256, 0, stream>>>(row_cls, q, extra_index, pooled);
  k_transform<<<B * 12, 256, 0, stream>>>(pooled, W_t, b_t, yb);
  k_lnscore<<<B, 256, 0, stream>>>(yb, gamma_t, beta_t, sel_ln, out);
}